// Round 31
// baseline (194.392 us; speedup 1.0000x reference)
//
#include <hip/hip_runtime.h>
#include <math.h>

#define EMB 1024
#define HEADS 16
#define HDIM 64
#define NBATCH 4
#define SEQ 2048
#define ROWS (NBATCH * SEQ)   // 8192
#define SCALE 0.125f          // 64^-0.5
#define QPRESCALE 0.18033688011112042f   // SCALE * log2(e), folded into q

typedef float f32x4 __attribute__((ext_vector_type(4)));
typedef float f32x16 __attribute__((ext_vector_type(16)));
typedef short bf16x8 __attribute__((ext_vector_type(8)));

__device__ inline unsigned short f2bf(float f) {
    unsigned int u = __builtin_bit_cast(unsigned int, f);
    u += 0x7fffu + ((u >> 16) & 1u);   // round-to-nearest-even
    return (unsigned short)(u >> 16);
}
// native 2^x: inputs bounded (|x|<~15) -> no denormal/range handling needed
__device__ inline float exp2fast(float x) {
    float y;
    asm("v_exp_f32 %0, %1" : "=v"(y) : "v"(x));
    return y;
}
// pack two f32 -> u32 of 2 bf16 (truncating) via v_perm_b32: {y.b3,y.b2,x.b3,x.b2}
__device__ inline unsigned int packbf(float x, float y) {
    return __builtin_amdgcn_perm(__builtin_bit_cast(unsigned int, y),
                                 __builtin_bit_cast(unsigned int, x), 0x07060302u);
}
__device__ inline bf16x8 mkfrag(unsigned int a, unsigned int b,
                                unsigned int c, unsigned int d) {
    union { unsigned int u[4]; bf16x8 v; } t;
    t.u[0] = a; t.u[1] = b; t.u[2] = c; t.u[3] = d;
    return t.v;
}

// ---------------- fused prep: wconv(w_qkv) | wconv(w_proj) | LayerNorm ----------------
__global__ __launch_bounds__(256) void prep(const float* __restrict__ x,
                                            const float* __restrict__ ln_w,
                                            const float* __restrict__ ln_b,
                                            const float* __restrict__ w_qkv,
                                            const float* __restrict__ w_proj,
                                            unsigned short* __restrict__ h,
                                            unsigned short* __restrict__ wqT,
                                            unsigned short* __restrict__ wpT) {
    __shared__ float t[32][33];
    int fb = blockIdx.x;
    if (fb < 4096) {
        const float* W;
        unsigned short* WT;
        int N, perm;
        if (fb < 3072) { W = w_qkv;  WT = wqT; N = 3072; perm = 1; }
        else           { W = w_proj; WT = wpT; N = 1024; perm = 0; fb -= 3072; }
        int k0 = (fb & 31) * 32, n0 = (fb >> 5) * 32;
        int tx = threadIdx.x & 31, ty = threadIdx.x >> 5;   // ty 0..7
        #pragma unroll
        for (int i = 0; i < 32; i += 8)
            t[ty + i][tx] = W[(size_t)(k0 + ty + i) * N + n0 + tx];
        __syncthreads();
        #pragma unroll
        for (int i = 0; i < 32; i += 8) {
            int n = n0 + ty + i;
            int dst = n;
            if (perm) {
                int head = n / 192;
                int rem = n - head * 192;
                int d = rem / 3;
                int which = rem - d * 3;
                dst = which * 1024 + head * 64 + d;
            }
            WT[(size_t)dst * EMB + k0 + tx] = f2bf(t[tx][ty + i]);
        }
    } else {
        int row = fb - 4096;
        const float* xr = x + (size_t)row * EMB;
        unsigned short* hr = h + (size_t)row * EMB;
        float4 v = ((const float4*)xr)[threadIdx.x];
        float s  = v.x + v.y + v.z + v.w;
        float ss = v.x*v.x + v.y*v.y + v.z*v.z + v.w*v.w;
        #pragma unroll
        for (int o = 32; o; o >>= 1) { s += __shfl_xor(s, o); ss += __shfl_xor(ss, o); }
        int wid = threadIdx.x >> 6;
        if ((threadIdx.x & 63) == 0) { t[0][wid] = s; t[0][4 + wid] = ss; }
        __syncthreads();
        if (threadIdx.x == 0) {
            t[0][0] = t[0][0] + t[0][1] + t[0][2] + t[0][3];
            t[0][4] = t[0][4] + t[0][5] + t[0][6] + t[0][7];
        }
        __syncthreads();
        float mu  = t[0][0] * (1.f / EMB);
        float var = t[0][4] * (1.f / EMB) - mu * mu;
        float rstd = rsqrtf(var + 1e-5f);
        float4 wv = ((const float4*)ln_w)[threadIdx.x];
        float4 bv = ((const float4*)ln_b)[threadIdx.x];
        ushort4 o;
        o.x = f2bf((v.x - mu) * rstd * wv.x + bv.x);
        o.y = f2bf((v.y - mu) * rstd * wv.y + bv.y);
        o.z = f2bf((v.z - mu) * rstd * wv.z + bv.z);
        o.w = f2bf((v.w - mu) * rstd * wv.w + bv.w);
        ((ushort4*)hr)[threadIdx.x] = o;
    }
}

// GEMM staging, BK=64: 128x64 bf16 tile (16KB), 4 gll/thread; linear LDS dest,
// INVERSE-swizzled global source (byte ^ ((row&7)<<4)); fragment reads apply
// the same XOR -> conflict-free with 16x16 fragment geometry (measured 0, r24).
#define GSTAGE64(LDSBUF, GPTR) do {                                                            \
    _Pragma("unroll")                                                                          \
    for (int i_ = 0; i_ < 4; ++i_) {                                                           \
        int phys_ = (i_ * 256 + tid) * 16;          /* byte in 16KB tile */                    \
        int row_ = phys_ >> 7;                      /* 0..127 */                               \
        int lg_  = (phys_ & 127) ^ ((row_ & 7) << 4);                                          \
        __builtin_amdgcn_global_load_lds(                                                      \
            (const __attribute__((address_space(1))) void*)                                    \
                ((const char*)(GPTR) + (size_t)row_ * (EMB * 2) + lg_),                        \
            (__attribute__((address_space(3))) void*)((char*)(LDSBUF) + i_ * 4096 + w * 1024), \
            16, 0, 0);                                                                         \
    }                                                                                          \
} while (0)

// ---------------- QKV GEMM bf16 MFMA 16x16x32: 128x128, BK=64, compute-covered drain ----------
__global__ __launch_bounds__(256, 3) void qkv_mfma(const unsigned short* __restrict__ A,
                                                const unsigned short* __restrict__ BT,
                                                const float* __restrict__ bias,
                                                unsigned short* __restrict__ qo,
                                                unsigned short* __restrict__ ko,
                                                unsigned short* __restrict__ vo) {
    __shared__ alignas(16) unsigned char As[16384];   // [128][128B] swizzled
    __shared__ alignas(16) unsigned char Bs[16384];
    int tid = threadIdx.x;
    int w = tid >> 6, lane = tid & 63, lg = lane >> 4, lr = lane & 15;
    int wr = w >> 1, wc = w & 1;
    int bid = blockIdx.x;                // 0..1535
    int local = bid >> 3;                // 0..191
    int bm = (bid & 7) * 8 + (local & 7);  // XCD-stripe of A rows
    int bn = local >> 3;                 // 0..23
    const unsigned short* Ab = A + (size_t)(bm * 128) * EMB;
    const unsigned short* Bb = BT + (size_t)(bn * 128) * EMB;
    f32x4 acc[4][4];
    #pragma unroll
    for (int m = 0; m < 4; ++m)
        #pragma unroll
        for (int n = 0; n < 4; ++n) acc[m][n] = (f32x4){0.f, 0.f, 0.f, 0.f};
    const int NI = EMB / 64;             // 16 K-steps
    GSTAGE64(As, Ab);
    GSTAGE64(Bs, Bb);
    __syncthreads();
    for (int it = 0; it < NI; ++it) {
        bf16x8 af[2][4], bf[2][4];
        #pragma unroll
        for (int kk = 0; kk < 2; ++kk) {
            #pragma unroll
            for (int m = 0; m < 4; ++m) {
                int arow = wr * 64 + m * 16 + lr;
                af[kk][m] = *(const bf16x8*)(As + arow * 128 +
                              ((lg * 16 + kk * 64) ^ ((arow & 7) << 4)));
            }
            #pragma unroll
            for (int n = 0; n < 4; ++n) {
                int brow = wc * 64 + n * 16 + lr;
                bf[kk][n] = *(const bf16x8*)(Bs + brow * 128 +
                              ((lg * 16 + kk * 64) ^ ((brow & 7) << 4)));
            }
        }
        __syncthreads();                 // all waves done reading; LDS reusable
        if (it + 1 < NI) {
            GSTAGE64(As, Ab + (it + 1) * 64);
            GSTAGE64(Bs, Bb + (it + 1) * 64);
        }
        #pragma unroll
        for (int kk = 0; kk < 2; ++kk)
            #pragma unroll
            for (int m = 0; m < 4; ++m)
                #pragma unroll
                for (int n = 0; n < 4; ++n)
                    acc[m][n] = __builtin_amdgcn_mfma_f32_16x16x32_bf16(af[kk][m], bf[kk][n], acc[m][n], 0, 0, 0);
        __syncthreads();                 // vmcnt drain, covered by MFMAs above
    }
    // epilogue: permuted column cp -> (which, head, d); bias via inverse perm
    int which = (bn * 128) >> 10;        // uniform per block (bn<8:q, <16:k, else v)
    if (which < 2) {
        #pragma unroll
        for (int n = 0; n < 4; ++n) {
            int cp = bn * 128 + wc * 64 + n * 16 + lr;
            int head = (cp >> 6) & 15;
            int d = cp & 63;
            float bv = bias[head * 192 + d * 3 + which];
            #pragma unroll
            for (int m = 0; m < 4; ++m) {
                #pragma unroll
                for (int r = 0; r < 4; ++r) {
                    int row = bm * 128 + wr * 64 + m * 16 + lg * 4 + r;
                    int bb = row >> 11;
                    int nq = row & 2047;
                    float val = acc[m][n][r] + bv;
                    if (which == 0)
                        qo[(((size_t)bb * HEADS + head) * SEQ + nq) * HDIM + d] = f2bf(val * QPRESCALE);
                    else
                        ko[(((size_t)bb * HEADS + head) * SEQ + nq) * HDIM + d] = f2bf(val);
                }
            }
        }
    } else {
        // V^T [d][n]: pack r=0..3 (4 consecutive nq) into one 8B store per (m,n)
        int row0 = bm * 128 + wr * 64 + lg * 4;       // + m*16
        int bb = row0 >> 11;                          // uniform per block (128 | 2048)
        int nq0 = row0 & 2047;
        #pragma unroll
        for (int n = 0; n < 4; ++n) {
            int cp = bn * 128 + wc * 64 + n * 16 + lr;
            int head = (cp >> 6) & 15;
            int d = cp & 63;
            float bv = bias[head * 192 + d * 3 + 2];
            unsigned short* vrow = vo + (((size_t)bb * HEADS + head) * HDIM + d) * SEQ;
            #pragma unroll
            for (int m = 0; m < 4; ++m) {
                ushort4 pk;
                pk.x = f2bf(acc[m][n][0] + bv);
                pk.y = f2bf(acc[m][n][1] + bv);
                pk.z = f2bf(acc[m][n][2] + bv);
                pk.w = f2bf(acc[m][n][3] + bv);
                *(ushort4*)&vrow[nq0 + m * 16] = pk;
            }
        }
    }
}

// ---------------- Flash attention v11: KVBLK=128, 8-wave 256-query blocks ----------------
// 16 tiles (was 32) -> half the barrier drains; LDS 64KB, residency unchanged
// (grid 512 = 2 blocks/CU either way). K tile = 128 rows x 128B = 16384 B
// (r30 bug: was kb*32768 -> OOB reads). V tile advance = 128 keys x 2B = 256 B.
#define STAGE(nb, kb_) do {                                                                        \
    _Pragma("unroll")                                                                              \
    for (int i_ = 0; i_ < 2; ++i_) {                                                               \
        int phys_ = i_ * 8192 + w * 1024 + lane * 16;   /* byte in 16KB tile */                    \
        int krow_ = phys_ >> 7;                         /* 0..127 */                               \
        int klg_  = (phys_ & 127) ^ ((krow_ & 7) << 4);                                            \
        __builtin_amdgcn_global_load_lds(                                                          \
            (const __attribute__((address_space(1))) void*)                                        \
                (kbytes + (size_t)(kb_) * 16384 + (size_t)krow_ * 128 + klg_),                     \
            (__attribute__((address_space(3))) void*)(&kls[nb][i_ * 8192 + w * 1024]), 16, 0, 0);  \
        int vrow_ = phys_ >> 8;                         /* 0..63 */                                \
        int vin_  = phys_ & 255;                                                                   \
        int vlg_  = vin_ ^ ((vrow_ & 7) << 4);                                                     \
        __builtin_amdgcn_global_load_lds(                                                          \
            (const __attribute__((address_space(1))) void*)                                        \
                (vbytes + (size_t)vrow_ * (SEQ * 2) + (size_t)(kb_) * 256 + vlg_),                 \
            (__attribute__((address_space(3))) void*)(&vls[nb][i_ * 8192 + w * 1024]), 16, 0, 0);  \
    }                                                                                              \
} while (0)

__global__ __launch_bounds__(512) void attn_mfma(const unsigned short* __restrict__ Q,
                                                 const unsigned short* __restrict__ K,
                                                 const unsigned short* __restrict__ VT,
                                                 unsigned short* __restrict__ AO) {
    __shared__ alignas(16) unsigned char kls[2][16384];  // [key][d] 128x128B, swizzled
    __shared__ alignas(16) unsigned char vls[2][16384];  // [d][key] 64x256B, swizzled
    int tid = threadIdx.x;
    int w = tid >> 6, lane = tid & 63;                   // w 0..7
    int col = lane & 31;
    int hi  = lane >> 5;
    // XCD swizzle (512 blocks, 8 XCDs): XCD c owns bh = 8c..8c+7 (4MB K/V = L2)
    int bid = blockIdx.x;
    int swz = (bid & 7) * 64 + (bid >> 3);
    int b  = swz >> 7;
    int hh = (swz >> 3) & 15;
    int qt = swz & 7;
    int q0 = qt * 256 + w * 32;
    size_t bh = ((size_t)b * HEADS + hh) * (size_t)SEQ * HDIM;
    const unsigned short* qp = Q + bh + (size_t)(q0 + col) * HDIM + 8 * hi;
    bf16x8 qB0 = *(const bf16x8*)(qp);
    bf16x8 qB1 = *(const bf16x8*)(qp + 16);
    bf16x8 qB2 = *(const bf16x8*)(qp + 32);
    bf16x8 qB3 = *(const bf16x8*)(qp + 48);
    f32x16 o0 = {0.f,0.f,0.f,0.f,0.f,0.f,0.f,0.f,0.f,0.f,0.f,0.f,0.f,0.f,0.f,0.f};
    f32x16 o1 = {0.f,0.f,0.f,0.f,0.f,0.f,0.f,0.f,0.f,0.f,0.f,0.f,0.f,0.f,0.f,0.f};
    float l = 0.f;
    const char* kbytes = (const char*)(K + bh);
    const char* vbytes = (const char*)(VT + bh);
    const int NT = SEQ / 128;                      // 16 tiles

    STAGE(0, 0);
    __syncthreads();
    for (int kb = 0; kb < NT; ++kb) {
        int cur = kb & 1;
        if (kb + 1 < NT) STAGE(cur ^ 1, kb + 1);
        const char* kcur = (const char*)&kls[cur][0];
        const char* vcur = (const char*)&vls[cur][0];
        #pragma unroll
        for (int t = 0; t < 4; ++t) {
            int keyl = t * 32 + col;
            int ksw = (keyl & 7) << 4;
            int kbs = keyl * 128;
            bf16x8 kf0 = *(const bf16x8*)(kcur + ((kbs +  0 + hi * 16) ^ ksw));
            bf16x8 kf1 = *(const bf16x8*)(kcur + ((kbs + 32 + hi * 16) ^ ksw));
            bf16x8 kf2 = *(const bf16x8*)(kcur + ((kbs + 64 + hi * 16) ^ ksw));
            bf16x8 kf3 = *(const bf16x8*)(kcur + ((kbs + 96 + hi * 16) ^ ksw));
            f32x16 s = {0.f,0.f,0.f,0.f,0.f,0.f,0.f,0.f,0.f,0.f,0.f,0.f,0.f,0.f,0.f,0.f};
            __builtin_amdgcn_s_setprio(1);
            s = __builtin_amdgcn_mfma_f32_32x32x16_bf16(kf0, qB0, s, 0, 0, 0);
            s = __builtin_amdgcn_mfma_f32_32x32x16_bf16(kf1, qB1, s, 0, 0, 0);
            s = __builtin_amdgcn_mfma_f32_32x32x16_bf16(kf2, qB2, s, 0, 0, 0);
            s = __builtin_amdgcn_mfma_f32_32x32x16_bf16(kf3, qB3, s, 0, 0, 0);
            __builtin_amdgcn_s_setprio(0);
            // ---- no-max softmax (q pre-scaled): p = 2^s via native v_exp_f32 ----
            float p[16];
            float lsa = 0.f, lsb = 0.f;
            #pragma unroll
            for (int r = 0; r < 16; r += 2) {
                p[r]     = exp2fast(s[r]);
                p[r + 1] = exp2fast(s[r + 1]);
                lsa += p[r];
                lsb += p[r + 1];
            }
            l += lsa + lsb;
            unsigned int pk0 = packbf(p[0], p[1]),   pk1 = packbf(p[2], p[3]);
            unsigned int pk2 = packbf(p[4], p[5]),   pk3 = packbf(p[6], p[7]);
            unsigned int pk4 = packbf(p[8], p[9]),   pk5 = packbf(p[10], p[11]);
            unsigned int pk6 = packbf(p[12], p[13]), pk7 = packbf(p[14], p[15]);
            asm volatile("v_permlane32_swap_b32 %0, %1" : "+v"(pk0), "+v"(pk2));
            asm volatile("v_permlane32_swap_b32 %0, %1" : "+v"(pk1), "+v"(pk3));
            asm volatile("v_permlane32_swap_b32 %0, %1" : "+v"(pk4), "+v"(pk6));
            asm volatile("v_permlane32_swap_b32 %0, %1" : "+v"(pk5), "+v"(pk7));
            bf16x8 pf0 = mkfrag(pk0, pk1, pk2, pk3);
            bf16x8 pf1 = mkfrag(pk4, pk5, pk6, pk7);
            int vsw = (col & 7) << 4;
            bf16x8 vf00 = *(const bf16x8*)(vcur + (col * 256) + (((t * 64) + hi * 16) ^ vsw));
            bf16x8 vf01 = *(const bf16x8*)(vcur + (col * 256) + (((t * 64) + 32 + hi * 16) ^ vsw));
            bf16x8 vf10 = *(const bf16x8*)(vcur + ((32 + col) * 256) + (((t * 64) + hi * 16) ^ vsw));
            bf16x8 vf11 = *(const bf16x8*)(vcur + ((32 + col) * 256) + (((t * 64) + 32 + hi * 16) ^ vsw));
            __builtin_amdgcn_s_setprio(1);
            o0 = __builtin_amdgcn_mfma_f32_32x32x16_bf16(pf0, vf00, o0, 0, 0, 0);
            o0 = __builtin_amdgcn_mfma_f32_32x32x16_bf16(pf1, vf01, o0, 0, 0, 0);
            o1 = __builtin_amdgcn_mfma_f32_32x32x16_bf16(pf0, vf10, o1, 0, 0, 0);
            o1 = __builtin_amdgcn_mfma_f32_32x32x16_bf16(pf1, vf11, o1, 0, 0, 0);
            __builtin_amdgcn_s_setprio(0);
        }
        if (kb + 1 < NT) __syncthreads();
    }
    float invc = 1.f / (l + __shfl_xor(l, 32));
    #pragma unroll
    for (int reg = 0; reg < 16; ++reg) {
        int crow = (reg & 3) + 8 * (reg >> 2) + 4 * hi;
        float invr = __shfl(invc, crow);
        int qq = q0 + crow;
        unsigned short* op = AO + ((size_t)b * SEQ + qq) * EMB + hh * HDIM + col;
        op[0]  = f2bf(o0[reg] * invr);
        op[32] = f2bf(o1[reg] * invr);
    }
}

// ---------------- Proj GEMM bf16 MFMA 16x16x32: 128x128, BK=64, compute-covered drain --------
__global__ __launch_bounds__(256, 3) void proj_mfma(const unsigned short* __restrict__ A,
                                                 const unsigned short* __restrict__ BT,
                                                 const float* __restrict__ bias,
                                                 const float* __restrict__ resid,
                                                 float* __restrict__ out) {
    __shared__ alignas(16) unsigned char As[16384];
    __shared__ alignas(16) unsigned char Bs[16384];
    int tid = threadIdx.x;
    int w = tid >> 6, lane = tid & 63, lg = lane >> 4, lr = lane & 15;
    int wr = w >> 1, wc = w & 1;
    int bid = blockIdx.x;                // 0..511
    int local = bid >> 3;                // 0..63
    int bm = (bid & 7) * 8 + (local & 7);
    int bn = local >> 3;                 // 0..7
    const unsigned short* Ab = A + (size_t)(bm * 128) * EMB;
    const unsigned short* Bb = BT + (size_t)(bn * 128) * EMB;
    f32x4 acc[4][4];
    #pragma unroll
    for (int m = 0; m < 4; ++m)
        #pragma unroll
        for (int n = 0; n < 4; ++n) acc[m][n] = (f32x4){0.f, 0.f, 0.f, 0.f};
    const int NI = EMB / 64;
    GSTAGE64(As, Ab);
    GSTAGE64(Bs, Bb);
    __syncthreads();
    for (int it = 0; it < NI; ++it) {
        bf16x8 af[2][4], bf[2][4];
        #pragma unroll
        for (int kk = 0; kk < 2; ++kk) {
            #pragma unroll
            for (int m = 0; m < 4; ++m) {
                int arow = wr * 64 + m * 16 + lr;
                af[kk][m] = *(const bf16x8*)(As + arow * 128 +
                              ((lg * 16 + kk * 64) ^ ((arow & 7) << 4)));
            }
            #pragma unroll
            for (int n = 0; n < 4; ++n) {
                int brow = wc * 64 + n * 16 + lr;
                bf[kk][n] = *(const bf16x8*)(Bs + brow * 128 +
                              ((lg * 16 + kk * 64) ^ ((brow & 7) << 4)));
            }
        }
        __syncthreads();
        if (it + 1 < NI) {
            GSTAGE64(As, Ab + (it + 1) * 64);
            GSTAGE64(Bs, Bb + (it + 1) * 64);
        }
        #pragma unroll
        for (int kk = 0; kk < 2; ++kk)
            #pragma unroll
            for (int m = 0; m < 4; ++m)
                #pragma unroll
                for (int n = 0; n < 4; ++n)
                    acc[m][n] = __builtin_amdgcn_mfma_f32_16x16x32_bf16(af[kk][m], bf[kk][n], acc[m][n], 0, 0, 0);
        __syncthreads();
    }
    #pragma unroll
    for (int n = 0; n < 4; ++n) {
        int c = bn * 128 + wc * 64 + n * 16 + lr;
        float bv = bias[c];
        #pragma unroll
        for (int m = 0; m < 4; ++m) {
            #pragma unroll
            for (int r = 0; r < 4; ++r) {
                size_t row = (size_t)bm * 128 + wr * 64 + m * 16 + lg * 4 + r;
                out[row * EMB + c] = acc[m][n][r] + bv + resid[row * EMB + c];
            }
        }
    }
}

extern "C" void kernel_launch(void* const* d_in, const int* in_sizes, int n_in,
                              void* d_out, int out_size, void* d_ws, size_t ws_size,
                              hipStream_t stream) {
    const float* x      = (const float*)d_in[0];
    const float* ln_w   = (const float*)d_in[1];
    const float* ln_b   = (const float*)d_in[2];
    const float* w_qkv  = (const float*)d_in[3];
    const float* b_qkv  = (const float*)d_in[4];
    const float* w_proj = (const float*)d_in[5];
    const float* b_proj = (const float*)d_in[6];
    float* out = (float*)d_out;

    char* ws = (char*)d_ws;
    const size_t MB16 = (size_t)ROWS * EMB * sizeof(unsigned short); // 16 MiB
    unsigned short* h   = (unsigned short*)ws;                // LN out (bf16)
    unsigned short* q   = (unsigned short*)(ws + MB16);       // pre-scaled by QPRESCALE
    unsigned short* k   = (unsigned short*)(ws + 2 * MB16);
    unsigned short* v   = (unsigned short*)(ws + 3 * MB16);   // [b][h][d][n]
    unsigned short* ao  = (unsigned short*)(ws + 4 * MB16);   // attn out (bf16)
    unsigned short* wqT = (unsigned short*)(ws + 5 * MB16);   // [3072][1024] PERMUTED rows
    unsigned short* wpT = (unsigned short*)(ws + 5 * MB16 + (size_t)3 * EMB * EMB * 2);

    prep<<<12288, 256, 0, stream>>>(x, ln_w, ln_b, w_qkv, w_proj, h, wqT, wpT);
    qkv_mfma<<<1536, 256, 0, stream>>>(h, wqT, b_qkv, q, k, v);
    attn_mfma<<<512, 512, 0, stream>>>(q, k, v, ao);
    proj_mfma<<<512, 256, 0, stream>>>(ao, wpT, b_proj, x, out);
}

// Round 32
// 188.786 us; speedup vs baseline: 1.0297x; 1.0297x over previous
//
#include <hip/hip_runtime.h>
#include <math.h>

#define EMB 1024
#define HEADS 16
#define HDIM 64
#define NBATCH 4
#define SEQ 2048
#define ROWS (NBATCH * SEQ)   // 8192
#define SCALE 0.125f          // 64^-0.5
#define QPRESCALE 0.18033688011112042f   // SCALE * log2(e), folded into q

typedef float f32x4 __attribute__((ext_vector_type(4)));
typedef float f32x16 __attribute__((ext_vector_type(16)));
typedef short bf16x8 __attribute__((ext_vector_type(8)));

__device__ inline unsigned short f2bf(float f) {
    unsigned int u = __builtin_bit_cast(unsigned int, f);
    u += 0x7fffu + ((u >> 16) & 1u);   // round-to-nearest-even
    return (unsigned short)(u >> 16);
}
// native 2^x: inputs bounded (|x|<~15) -> no denormal/range handling needed
__device__ inline float exp2fast(float x) {
    float y;
    asm("v_exp_f32 %0, %1" : "=v"(y) : "v"(x));
    return y;
}
// pack two f32 -> u32 of 2 bf16 (truncating) via v_perm_b32: {y.b3,y.b2,x.b3,x.b2}
__device__ inline unsigned int packbf(float x, float y) {
    return __builtin_amdgcn_perm(__builtin_bit_cast(unsigned int, y),
                                 __builtin_bit_cast(unsigned int, x), 0x07060302u);
}
__device__ inline bf16x8 mkfrag(unsigned int a, unsigned int b,
                                unsigned int c, unsigned int d) {
    union { unsigned int u[4]; bf16x8 v; } t;
    t.u[0] = a; t.u[1] = b; t.u[2] = c; t.u[3] = d;
    return t.v;
}

// ---------------- fused prep: wconv(w_qkv) | wconv(w_proj) | LayerNorm ----------------
__global__ __launch_bounds__(256) void prep(const float* __restrict__ x,
                                            const float* __restrict__ ln_w,
                                            const float* __restrict__ ln_b,
                                            const float* __restrict__ w_qkv,
                                            const float* __restrict__ w_proj,
                                            unsigned short* __restrict__ h,
                                            unsigned short* __restrict__ wqT,
                                            unsigned short* __restrict__ wpT) {
    __shared__ float t[32][33];
    int fb = blockIdx.x;
    if (fb < 4096) {
        const float* W;
        unsigned short* WT;
        int N, perm;
        if (fb < 3072) { W = w_qkv;  WT = wqT; N = 3072; perm = 1; }
        else           { W = w_proj; WT = wpT; N = 1024; perm = 0; fb -= 3072; }
        int k0 = (fb & 31) * 32, n0 = (fb >> 5) * 32;
        int tx = threadIdx.x & 31, ty = threadIdx.x >> 5;   // ty 0..7
        #pragma unroll
        for (int i = 0; i < 32; i += 8)
            t[ty + i][tx] = W[(size_t)(k0 + ty + i) * N + n0 + tx];
        __syncthreads();
        #pragma unroll
        for (int i = 0; i < 32; i += 8) {
            int n = n0 + ty + i;
            int dst = n;
            if (perm) {
                int head = n / 192;
                int rem = n - head * 192;
                int d = rem / 3;
                int which = rem - d * 3;
                dst = which * 1024 + head * 64 + d;
            }
            WT[(size_t)dst * EMB + k0 + tx] = f2bf(t[tx][ty + i]);
        }
    } else {
        int row = fb - 4096;
        const float* xr = x + (size_t)row * EMB;
        unsigned short* hr = h + (size_t)row * EMB;
        float4 v = ((const float4*)xr)[threadIdx.x];
        float s  = v.x + v.y + v.z + v.w;
        float ss = v.x*v.x + v.y*v.y + v.z*v.z + v.w*v.w;
        #pragma unroll
        for (int o = 32; o; o >>= 1) { s += __shfl_xor(s, o); ss += __shfl_xor(ss, o); }
        int wid = threadIdx.x >> 6;
        if ((threadIdx.x & 63) == 0) { t[0][wid] = s; t[0][4 + wid] = ss; }
        __syncthreads();
        if (threadIdx.x == 0) {
            t[0][0] = t[0][0] + t[0][1] + t[0][2] + t[0][3];
            t[0][4] = t[0][4] + t[0][5] + t[0][6] + t[0][7];
        }
        __syncthreads();
        float mu  = t[0][0] * (1.f / EMB);
        float var = t[0][4] * (1.f / EMB) - mu * mu;
        float rstd = rsqrtf(var + 1e-5f);
        float4 wv = ((const float4*)ln_w)[threadIdx.x];
        float4 bv = ((const float4*)ln_b)[threadIdx.x];
        ushort4 o;
        o.x = f2bf((v.x - mu) * rstd * wv.x + bv.x);
        o.y = f2bf((v.y - mu) * rstd * wv.y + bv.y);
        o.z = f2bf((v.z - mu) * rstd * wv.z + bv.z);
        o.w = f2bf((v.w - mu) * rstd * wv.w + bv.w);
        ((ushort4*)hr)[threadIdx.x] = o;
    }
}

// GEMM staging, BK=64: 128x64 bf16 tile (16KB), 4 gll/thread; linear LDS dest,
// INVERSE-swizzled global source (byte ^ ((row&7)<<4)); fragment reads apply
// the same XOR -> conflict-free with 16x16 fragment geometry (measured 0, r24).
#define GSTAGE64(LDSBUF, GPTR) do {                                                            \
    _Pragma("unroll")                                                                          \
    for (int i_ = 0; i_ < 4; ++i_) {                                                           \
        int phys_ = (i_ * 256 + tid) * 16;          /* byte in 16KB tile */                    \
        int row_ = phys_ >> 7;                      /* 0..127 */                               \
        int lg_  = (phys_ & 127) ^ ((row_ & 7) << 4);                                          \
        __builtin_amdgcn_global_load_lds(                                                      \
            (const __attribute__((address_space(1))) void*)                                    \
                ((const char*)(GPTR) + (size_t)row_ * (EMB * 2) + lg_),                        \
            (__attribute__((address_space(3))) void*)((char*)(LDSBUF) + i_ * 4096 + w * 1024), \
            16, 0, 0);                                                                         \
    }                                                                                          \
} while (0)

// ---------------- QKV GEMM bf16 MFMA 16x16x32: 128x128, BK=64, compute-covered drain ----------
// Loop: read ALL fragments -> regs; barrier (LDS free); issue next-step gll (async);
// 32 MFMAs cover the gll L2 latency; barrier's vmcnt drain then nearly free.
// V^T epilogue: r=0..3 are 4 consecutive nq in ONE thread -> pack into 8B stores.
__global__ __launch_bounds__(256, 3) void qkv_mfma(const unsigned short* __restrict__ A,
                                                const unsigned short* __restrict__ BT,
                                                const float* __restrict__ bias,
                                                unsigned short* __restrict__ qo,
                                                unsigned short* __restrict__ ko,
                                                unsigned short* __restrict__ vo) {
    __shared__ alignas(16) unsigned char As[16384];   // [128][128B] swizzled
    __shared__ alignas(16) unsigned char Bs[16384];
    int tid = threadIdx.x;
    int w = tid >> 6, lane = tid & 63, lg = lane >> 4, lr = lane & 15;
    int wr = w >> 1, wc = w & 1;
    int bid = blockIdx.x;                // 0..1535
    int local = bid >> 3;                // 0..191
    int bm = (bid & 7) * 8 + (local & 7);  // XCD-stripe of A rows
    int bn = local >> 3;                 // 0..23
    const unsigned short* Ab = A + (size_t)(bm * 128) * EMB;
    const unsigned short* Bb = BT + (size_t)(bn * 128) * EMB;
    f32x4 acc[4][4];
    #pragma unroll
    for (int m = 0; m < 4; ++m)
        #pragma unroll
        for (int n = 0; n < 4; ++n) acc[m][n] = (f32x4){0.f, 0.f, 0.f, 0.f};
    const int NI = EMB / 64;             // 16 K-steps
    GSTAGE64(As, Ab);
    GSTAGE64(Bs, Bb);
    __syncthreads();
    for (int it = 0; it < NI; ++it) {
        bf16x8 af[2][4], bf[2][4];
        #pragma unroll
        for (int kk = 0; kk < 2; ++kk) {
            #pragma unroll
            for (int m = 0; m < 4; ++m) {
                int arow = wr * 64 + m * 16 + lr;
                af[kk][m] = *(const bf16x8*)(As + arow * 128 +
                              ((lg * 16 + kk * 64) ^ ((arow & 7) << 4)));
            }
            #pragma unroll
            for (int n = 0; n < 4; ++n) {
                int brow = wc * 64 + n * 16 + lr;
                bf[kk][n] = *(const bf16x8*)(Bs + brow * 128 +
                              ((lg * 16 + kk * 64) ^ ((brow & 7) << 4)));
            }
        }
        __syncthreads();                 // all waves done reading; LDS reusable
        if (it + 1 < NI) {
            GSTAGE64(As, Ab + (it + 1) * 64);
            GSTAGE64(Bs, Bb + (it + 1) * 64);
        }
        #pragma unroll
        for (int kk = 0; kk < 2; ++kk)
            #pragma unroll
            for (int m = 0; m < 4; ++m)
                #pragma unroll
                for (int n = 0; n < 4; ++n)
                    acc[m][n] = __builtin_amdgcn_mfma_f32_16x16x32_bf16(af[kk][m], bf[kk][n], acc[m][n], 0, 0, 0);
        __syncthreads();                 // vmcnt drain, covered by MFMAs above
    }
    // epilogue: permuted column cp -> (which, head, d); bias via inverse perm
    int which = (bn * 128) >> 10;        // uniform per block (bn<8:q, <16:k, else v)
    if (which < 2) {
        #pragma unroll
        for (int n = 0; n < 4; ++n) {
            int cp = bn * 128 + wc * 64 + n * 16 + lr;
            int head = (cp >> 6) & 15;
            int d = cp & 63;
            float bv = bias[head * 192 + d * 3 + which];
            #pragma unroll
            for (int m = 0; m < 4; ++m) {
                #pragma unroll
                for (int r = 0; r < 4; ++r) {
                    int row = bm * 128 + wr * 64 + m * 16 + lg * 4 + r;
                    int bb = row >> 11;
                    int nq = row & 2047;
                    float val = acc[m][n][r] + bv;
                    if (which == 0)
                        qo[(((size_t)bb * HEADS + head) * SEQ + nq) * HDIM + d] = f2bf(val * QPRESCALE);
                    else
                        ko[(((size_t)bb * HEADS + head) * SEQ + nq) * HDIM + d] = f2bf(val);
                }
            }
        }
    } else {
        // V^T [d][n]: pack r=0..3 (4 consecutive nq) into one 8B store per (m,n)
        int row0 = bm * 128 + wr * 64 + lg * 4;       // + m*16
        int bb = row0 >> 11;                          // uniform per block (128 | 2048)
        int nq0 = row0 & 2047;
        #pragma unroll
        for (int n = 0; n < 4; ++n) {
            int cp = bn * 128 + wc * 64 + n * 16 + lr;
            int head = (cp >> 6) & 15;
            int d = cp & 63;
            float bv = bias[head * 192 + d * 3 + 2];
            unsigned short* vrow = vo + (((size_t)bb * HEADS + head) * HDIM + d) * SEQ;
            #pragma unroll
            for (int m = 0; m < 4; ++m) {
                ushort4 pk;
                pk.x = f2bf(acc[m][n][0] + bv);
                pk.y = f2bf(acc[m][n][1] + bv);
                pk.z = f2bf(acc[m][n][2] + bv);
                pk.w = f2bf(acc[m][n][3] + bv);
                *(ushort4*)&vrow[nq0 + m * 16] = pk;
            }
        }
    }
}

// ---------------- Flash attention v10: KVBLK=64, 8-wave 256-query blocks (r29 best) ----------
#define STAGE(nb, kb_) do {                                                                        \
    int off_ = sbase + lane * 16;               /* physical byte in 8KB tile */                    \
    int row_ = off_ >> 7;                                                                          \
    int lg_  = off_ ^ ((row_ & 7) << 4);        /* logical byte (involution) */                    \
    __builtin_amdgcn_global_load_lds(                                                              \
        (const __attribute__((address_space(1))) void*)(kbytes + (size_t)(kb_) * 8192 + lg_),      \
        (__attribute__((address_space(3))) void*)(&kls[nb][sbase]), 16, 0, 0);                     \
    __builtin_amdgcn_global_load_lds(                                                              \
        (const __attribute__((address_space(1))) void*)(vbytes + (size_t)row_ * (SEQ * 2)          \
                                         + (size_t)(kb_) * 128 + (lg_ & 127)),                     \
        (__attribute__((address_space(3))) void*)(&vls[nb][sbase]), 16, 0, 0);                     \
} while (0)

__global__ __launch_bounds__(512) void attn_mfma(const unsigned short* __restrict__ Q,
                                                 const unsigned short* __restrict__ K,
                                                 const unsigned short* __restrict__ VT,
                                                 unsigned short* __restrict__ AO) {
    __shared__ alignas(16) unsigned char kls[2][8192];   // [key][d] 64x128B, swizzled
    __shared__ alignas(16) unsigned char vls[2][8192];   // [d][key] 64x128B, swizzled
    int tid = threadIdx.x;
    int w = tid >> 6, lane = tid & 63;                   // w 0..7
    int col = lane & 31;
    int hi  = lane >> 5;
    // XCD swizzle (512 blocks, 8 XCDs): XCD c owns bh = 8c..8c+7 (4MB K/V = L2)
    int bid = blockIdx.x;
    int swz = (bid & 7) * 64 + (bid >> 3);
    int b  = swz >> 7;
    int hh = (swz >> 3) & 15;
    int qt = swz & 7;
    int q0 = qt * 256 + w * 32;
    size_t bh = ((size_t)b * HEADS + hh) * (size_t)SEQ * HDIM;
    const unsigned short* qp = Q + bh + (size_t)(q0 + col) * HDIM + 8 * hi;
    bf16x8 qB0 = *(const bf16x8*)(qp);
    bf16x8 qB1 = *(const bf16x8*)(qp + 16);
    bf16x8 qB2 = *(const bf16x8*)(qp + 32);
    bf16x8 qB3 = *(const bf16x8*)(qp + 48);
    f32x16 o0 = {0.f,0.f,0.f,0.f,0.f,0.f,0.f,0.f,0.f,0.f,0.f,0.f,0.f,0.f,0.f,0.f};
    f32x16 o1 = {0.f,0.f,0.f,0.f,0.f,0.f,0.f,0.f,0.f,0.f,0.f,0.f,0.f,0.f,0.f,0.f};
    float l = 0.f;
    const char* kbytes = (const char*)(K + bh);
    const char* vbytes = (const char*)(VT + bh);
    const int NT = SEQ / 64;                       // 32 tiles
    int sbase = w * 1024;                          // this wave's 1KB staging chunk

    STAGE(0, 0);
    __syncthreads();
    for (int kb = 0; kb < NT; ++kb) {
        int cur = kb & 1;
        if (kb + 1 < NT) STAGE(cur ^ 1, kb + 1);
        const char* kcur = (const char*)&kls[cur][0];
        const char* vcur = (const char*)&vls[cur][0];
        #pragma unroll
        for (int t = 0; t < 2; ++t) {
            int keyl = t * 32 + col;
            int ksw = (keyl & 7) << 4;
            int kbs = keyl * 128;
            bf16x8 kf0 = *(const bf16x8*)(kcur + ((kbs +  0 + hi * 16) ^ ksw));
            bf16x8 kf1 = *(const bf16x8*)(kcur + ((kbs + 32 + hi * 16) ^ ksw));
            bf16x8 kf2 = *(const bf16x8*)(kcur + ((kbs + 64 + hi * 16) ^ ksw));
            bf16x8 kf3 = *(const bf16x8*)(kcur + ((kbs + 96 + hi * 16) ^ ksw));
            f32x16 s = {0.f,0.f,0.f,0.f,0.f,0.f,0.f,0.f,0.f,0.f,0.f,0.f,0.f,0.f,0.f,0.f};
            __builtin_amdgcn_s_setprio(1);
            s = __builtin_amdgcn_mfma_f32_32x32x16_bf16(kf0, qB0, s, 0, 0, 0);
            s = __builtin_amdgcn_mfma_f32_32x32x16_bf16(kf1, qB1, s, 0, 0, 0);
            s = __builtin_amdgcn_mfma_f32_32x32x16_bf16(kf2, qB2, s, 0, 0, 0);
            s = __builtin_amdgcn_mfma_f32_32x32x16_bf16(kf3, qB3, s, 0, 0, 0);
            __builtin_amdgcn_s_setprio(0);
            // ---- no-max softmax (q pre-scaled): p = 2^s via native v_exp_f32 ----
            float p[16];
            float lsa = 0.f, lsb = 0.f;
            #pragma unroll
            for (int r = 0; r < 16; r += 2) {
                p[r]     = exp2fast(s[r]);
                p[r + 1] = exp2fast(s[r + 1]);
                lsa += p[r];
                lsb += p[r + 1];
            }
            l += lsa + lsb;
            unsigned int pk0 = packbf(p[0], p[1]),   pk1 = packbf(p[2], p[3]);
            unsigned int pk2 = packbf(p[4], p[5]),   pk3 = packbf(p[6], p[7]);
            unsigned int pk4 = packbf(p[8], p[9]),   pk5 = packbf(p[10], p[11]);
            unsigned int pk6 = packbf(p[12], p[13]), pk7 = packbf(p[14], p[15]);
            asm volatile("v_permlane32_swap_b32 %0, %1" : "+v"(pk0), "+v"(pk2));
            asm volatile("v_permlane32_swap_b32 %0, %1" : "+v"(pk1), "+v"(pk3));
            asm volatile("v_permlane32_swap_b32 %0, %1" : "+v"(pk4), "+v"(pk6));
            asm volatile("v_permlane32_swap_b32 %0, %1" : "+v"(pk5), "+v"(pk7));
            bf16x8 pf0 = mkfrag(pk0, pk1, pk2, pk3);
            bf16x8 pf1 = mkfrag(pk4, pk5, pk6, pk7);
            int vsw = (col & 7) << 4;
            int vb0 = col * 128 + t * 64;
            int vb1 = (32 + col) * 128 + t * 64;
            bf16x8 vf00 = *(const bf16x8*)(vcur + ((vb0 + hi * 16) ^ vsw));
            bf16x8 vf01 = *(const bf16x8*)(vcur + ((vb0 + 32 + hi * 16) ^ vsw));
            bf16x8 vf10 = *(const bf16x8*)(vcur + ((vb1 + hi * 16) ^ vsw));
            bf16x8 vf11 = *(const bf16x8*)(vcur + ((vb1 + 32 + hi * 16) ^ vsw));
            __builtin_amdgcn_s_setprio(1);
            o0 = __builtin_amdgcn_mfma_f32_32x32x16_bf16(pf0, vf00, o0, 0, 0, 0);
            o0 = __builtin_amdgcn_mfma_f32_32x32x16_bf16(pf1, vf01, o0, 0, 0, 0);
            o1 = __builtin_amdgcn_mfma_f32_32x32x16_bf16(pf0, vf10, o1, 0, 0, 0);
            o1 = __builtin_amdgcn_mfma_f32_32x32x16_bf16(pf1, vf11, o1, 0, 0, 0);
            __builtin_amdgcn_s_setprio(0);
        }
        if (kb + 1 < NT) __syncthreads();
    }
    float invc = 1.f / (l + __shfl_xor(l, 32));
    #pragma unroll
    for (int reg = 0; reg < 16; ++reg) {
        int crow = (reg & 3) + 8 * (reg >> 2) + 4 * hi;
        float invr = __shfl(invc, crow);
        int qq = q0 + crow;
        unsigned short* op = AO + ((size_t)b * SEQ + qq) * EMB + hh * HDIM + col;
        op[0]  = f2bf(o0[reg] * invr);
        op[32] = f2bf(o1[reg] * invr);
    }
}

// ---------------- Proj GEMM bf16 MFMA 16x16x32: 128x128, BK=64, compute-covered drain --------
__global__ __launch_bounds__(256, 3) void proj_mfma(const unsigned short* __restrict__ A,
                                                 const unsigned short* __restrict__ BT,
                                                 const float* __restrict__ bias,
                                                 const float* __restrict__ resid,
                                                 float* __restrict__ out) {
    __shared__ alignas(16) unsigned char As[16384];
    __shared__ alignas(16) unsigned char Bs[16384];
    int tid = threadIdx.x;
    int w = tid >> 6, lane = tid & 63, lg = lane >> 4, lr = lane & 15;
    int wr = w >> 1, wc = w & 1;
    int bid = blockIdx.x;                // 0..511
    int local = bid >> 3;                // 0..63
    int bm = (bid & 7) * 8 + (local & 7);
    int bn = local >> 3;                 // 0..7
    const unsigned short* Ab = A + (size_t)(bm * 128) * EMB;
    const unsigned short* Bb = BT + (size_t)(bn * 128) * EMB;
    f32x4 acc[4][4];
    #pragma unroll
    for (int m = 0; m < 4; ++m)
        #pragma unroll
        for (int n = 0; n < 4; ++n) acc[m][n] = (f32x4){0.f, 0.f, 0.f, 0.f};
    const int NI = EMB / 64;
    GSTAGE64(As, Ab);
    GSTAGE64(Bs, Bb);
    __syncthreads();
    for (int it = 0; it < NI; ++it) {
        bf16x8 af[2][4], bf[2][4];
        #pragma unroll
        for (int kk = 0; kk < 2; ++kk) {
            #pragma unroll
            for (int m = 0; m < 4; ++m) {
                int arow = wr * 64 + m * 16 + lr;
                af[kk][m] = *(const bf16x8*)(As + arow * 128 +
                              ((lg * 16 + kk * 64) ^ ((arow & 7) << 4)));
            }
            #pragma unroll
            for (int n = 0; n < 4; ++n) {
                int brow = wc * 64 + n * 16 + lr;
                bf[kk][n] = *(const bf16x8*)(Bs + brow * 128 +
                              ((lg * 16 + kk * 64) ^ ((brow & 7) << 4)));
            }
        }
        __syncthreads();
        if (it + 1 < NI) {
            GSTAGE64(As, Ab + (it + 1) * 64);
            GSTAGE64(Bs, Bb + (it + 1) * 64);
        }
        #pragma unroll
        for (int kk = 0; kk < 2; ++kk)
            #pragma unroll
            for (int m = 0; m < 4; ++m)
                #pragma unroll
                for (int n = 0; n < 4; ++n)
                    acc[m][n] = __builtin_amdgcn_mfma_f32_16x16x32_bf16(af[kk][m], bf[kk][n], acc[m][n], 0, 0, 0);
        __syncthreads();
    }
    #pragma unroll
    for (int n = 0; n < 4; ++n) {
        int c = bn * 128 + wc * 64 + n * 16 + lr;
        float bv = bias[c];
        #pragma unroll
        for (int m = 0; m < 4; ++m) {
            #pragma unroll
            for (int r = 0; r < 4; ++r) {
                size_t row = (size_t)bm * 128 + wr * 64 + m * 16 + lg * 4 + r;
                out[row * EMB + c] = acc[m][n][r] + bv + resid[row * EMB + c];
            }
        }
    }
}

extern "C" void kernel_launch(void* const* d_in, const int* in_sizes, int n_in,
                              void* d_out, int out_size, void* d_ws, size_t ws_size,
                              hipStream_t stream) {
    const float* x      = (const float*)d_in[0];
    const float* ln_w   = (const float*)d_in[1];
    const float* ln_b   = (const float*)d_in[2];
    const float* w_qkv  = (const float*)d_in[3];
    const float* b_qkv  = (const float*)d_in[4];
    const float* w_proj = (const float*)d_in[5];
    const float* b_proj = (const float*)d_in[6];
    float* out = (float*)d_out;

    char* ws = (char*)d_ws;
    const size_t MB16 = (size_t)ROWS * EMB * sizeof(unsigned short); // 16 MiB
    unsigned short* h   = (unsigned short*)ws;                // LN out (bf16)
    unsigned short* q   = (unsigned short*)(ws + MB16);       // pre-scaled by QPRESCALE
    unsigned short* k   = (unsigned short*)(ws + 2 * MB16);
    unsigned short* v   = (unsigned short*)(ws + 3 * MB16);   // [b][h][d][n]
    unsigned short* ao  = (unsigned short*)(ws + 4 * MB16);   // attn out (bf16)
    unsigned short* wqT = (unsigned short*)(ws + 5 * MB16);   // [3072][1024] PERMUTED rows
    unsigned short* wpT = (unsigned short*)(ws + 5 * MB16 + (size_t)3 * EMB * EMB * 2);

    prep<<<12288, 256, 0, stream>>>(x, ln_w, ln_b, w_qkv, w_proj, h, wqT, wpT);
    qkv_mfma<<<1536, 256, 0, stream>>>(h, wqT, b_qkv, q, k, v);
    attn_mfma<<<512, 512, 0, stream>>>(q, k, v, ao);
    proj_mfma<<<512, 256, 0, stream>>>(ao, wpT, b_proj, x, out);
}